// Round 1
// baseline (110.374 us; speedup 1.0000x reference)
//
#include <hip/hip_runtime.h>

// NT-Xent: BATCH=4096, DIM=512, TEMP=0.5
// loss = mean_i [ log(sum_{j!=i} exp(2*cos(z_i,z_j))) - 2*cos(z_i, z_partner) ]
// R6: software-pipelined fp8 MX GEMM. Double-buffered LDS, stage(k+1) issued
// before waiting on stage(k) with counted s_waitcnt vmcnt(8) + raw s_barrier
// (T3+T4), pure-MFMA cluster under s_setprio (T5), XCD-chunked block swizzle.
// Diag blocks stage B redundantly to keep 8 loads/wave/stage (uniform vmcnt).

#define NROWS 8192
#define HALF_N 4096
#define KD 512            // elements per row (= 512 B/row in fp8)
#define TILE 128
#define BK 128            // fp8 bytes of K per tile (8 chunks of 16 B per row)
#define NT (NROWS / TILE) // 64 block-tiles per side
#define NBLK (NT * (NT + 1) / 2)  // 2080 (divisible by 8)

typedef unsigned char u8;
typedef __attribute__((ext_vector_type(4))) int i32x4;
typedef __attribute__((ext_vector_type(8))) int i32x8;
typedef __attribute__((ext_vector_type(4))) float f32x4;

__device__ inline void load16_to_lds(const u8* g, u8* l) {
  __builtin_amdgcn_global_load_lds((const __attribute__((address_space(1))) void*)g,
                                   (__attribute__((address_space(3))) void*)l,
                                   16, 0, 0);
}

// ---------------- normalize: z (fp32) -> zq (fp8 e4m3, unit rows) ------------
// wave-per-row: 4 rows/block, 2048 blocks. Also zeroes rowsum/possum/out.
__global__ __launch_bounds__(256) void nt_normalize(const float* __restrict__ zi,
                                                    const float* __restrict__ zj,
                                                    u8* __restrict__ zq,
                                                    float* __restrict__ rowsum,
                                                    float* __restrict__ possum,
                                                    float* __restrict__ out) {
  const int t = threadIdx.x;
  if (t < 4) rowsum[blockIdx.x * 4 + t] = 0.f;
  if (blockIdx.x == 0 && t == 4) { possum[0] = 0.f; out[0] = 0.f; }

  const int wave = t >> 6, lane = t & 63;
  const int row = blockIdx.x * 4 + wave;
  const float* src = (row < HALF_N) ? (zi + (size_t)row * KD)
                                    : (zj + (size_t)(row - HALF_N) * KD);
  const float4 v0 = ((const float4*)src)[lane * 2];
  const float4 v1 = ((const float4*)src)[lane * 2 + 1];
  float ss = v0.x * v0.x + v0.y * v0.y + v0.z * v0.z + v0.w * v0.w +
             v1.x * v1.x + v1.y * v1.y + v1.z * v1.z + v1.w * v1.w;
#pragma unroll
  for (int m = 1; m < 64; m <<= 1) ss += __shfl_xor(ss, m);
  const float inv = rsqrtf(ss);              // norms ~22.6, EPS irrelevant
  int lo = __builtin_amdgcn_cvt_pk_fp8_f32(v0.x * inv, v0.y * inv, 0, false);
  lo = __builtin_amdgcn_cvt_pk_fp8_f32(v0.z * inv, v0.w * inv, lo, true);
  int hi = __builtin_amdgcn_cvt_pk_fp8_f32(v1.x * inv, v1.y * inv, 0, false);
  hi = __builtin_amdgcn_cvt_pk_fp8_f32(v1.z * inv, v1.w * inv, hi, true);
  ((int2*)(zq + (size_t)row * KD))[lane] = make_int2(lo, hi);
}

// ---------------- GEMM + fused epilogue (upper-triangular blocks) ----------
// 128x128 tile per block, 4 waves in 2x2, each wave 4x4 MFMA tiles of 16x16,
// one mfma_scale_f32_16x16x128 per tile-pair per K-iteration (BK=128).
// LDS holds 16B chunks at r*8 + (c ^ (r&7)) (XOR swizzle -> min bank conflicts).
// Pipeline per iter k: [issue stage(k+1) into buf^1] -> s_waitcnt vmcnt(8)
// (oldest 8 = stage(k)) -> s_barrier -> frag loads + MFMA cluster ->
// lgkmcnt(0) -> s_barrier (buffer free for overwrite next iter).
__global__ __launch_bounds__(256) void nt_gemm(const u8* __restrict__ zq,
                                               float* __restrict__ rowsum,
                                               float* __restrict__ possum) {
  __shared__ __attribute__((aligned(16))) u8 lA[2][TILE * BK];
  __shared__ __attribute__((aligned(16))) u8 lB[2][TILE * BK];
  __shared__ float lrow[TILE];
  __shared__ float lcol[TILE];

  // XCD-chunked bijective swizzle (NBLK % 8 == 0): consecutive work items
  // (same tm -> shared A panel) land on the same XCD's private L2.
  const int bid = (blockIdx.x & 7) * (NBLK / 8) + (blockIdx.x >> 3);

  // decode linear bid -> (tm, tn) with tn >= tm
  int tm = (int)((float)(2 * NT + 1) * 0.5f -
                 sqrtf((float)(2 * NT + 1) * (float)(2 * NT + 1) * 0.25f - 2.0f * (float)bid));
  if (tm < 0) tm = 0;
  if (tm > NT - 1) tm = NT - 1;
  while ((tm + 1) * NT - ((tm + 1) * tm) / 2 <= bid) ++tm;
  while (tm * NT - (tm * (tm - 1)) / 2 > bid) --tm;
  const int tn = tm + (bid - (tm * NT - (tm * (tm - 1)) / 2));
  const bool diag = (tm == tn);
  const bool isPos = (tn - tm == 32);   // block diagonal holds sim[i][i+N]

  const int t = threadIdx.x;
  const int wave = t >> 6, lane = t & 63;
  const int wm = wave >> 1, wn = wave & 1;
  const int c16 = lane & 15, quad = lane >> 4;
  const int q2 = quad * 2;

  const int rowA = tm * TILE, rowB = tn * TILE;

  f32x4 acc[4][4] = {};

  // stage one 128x128 fp8 A-tile + B-tile (k0 byte offset) into buffer buf.
  // 8 global_load_lds per wave, always (diag blocks redundantly load B so the
  // in-flight count is uniform -> exact vmcnt literals).
  auto stage = [&](int k0, int buf) {
#pragma unroll
    for (int it = 0; it < 4; ++it) {
      const int chunk = it * 256 + t;           // destination chunk position
      const int r = chunk >> 3, cpos = chunk & 7;
      const int c = cpos ^ (r & 7);             // source column chunk (swizzle)
      u8* dstA = &lA[buf][(it * 256 + wave * 64) * 16];  // wave-uniform
      u8* dstB = &lB[buf][(it * 256 + wave * 64) * 16];
      load16_to_lds(&zq[(size_t)(rowA + r) * KD + k0 + c * 16], dstA);
      load16_to_lds(&zq[(size_t)(rowB + r) * KD + k0 + c * 16], dstB);
    }
  };

  stage(0, 0);  // prologue: fill buffer 0

#pragma unroll
  for (int k = 0; k < 4; ++k) {
    const int cur = k & 1;
    if (k < 3) {
      stage((k + 1) * BK, cur ^ 1);                    // 8 more in flight
      asm volatile("s_waitcnt vmcnt(8)" ::: "memory"); // oldest 8 = stage(k)
    } else {
      asm volatile("s_waitcnt vmcnt(0)" ::: "memory");
    }
    __builtin_amdgcn_s_barrier();          // all waves' stage(k) now in LDS
    __builtin_amdgcn_sched_barrier(0);

    const u8* Ab = lA[cur];
    const u8* Bb = lB[cur];

    i32x8 bg[4], ag[4];
#pragma unroll
    for (int ni = 0; ni < 4; ++ni) {
      const int rB = wn * 64 + ni * 16 + c16;
      const i32x4 bl = *(const i32x4*)&Bb[(rB * 8 + (q2 ^ (rB & 7))) * 16];
      const i32x4 bh = *(const i32x4*)&Bb[(rB * 8 + ((q2 + 1) ^ (rB & 7))) * 16];
      bg[ni] = (i32x8){bl[0], bl[1], bl[2], bl[3], bh[0], bh[1], bh[2], bh[3]};
    }
#pragma unroll
    for (int mi = 0; mi < 4; ++mi) {
      const int rA = wm * 64 + mi * 16 + c16;
      const i32x4 al = *(const i32x4*)&Ab[(rA * 8 + (q2 ^ (rA & 7))) * 16];
      const i32x4 ah = *(const i32x4*)&Ab[(rA * 8 + ((q2 + 1) ^ (rA & 7))) * 16];
      ag[mi] = (i32x8){al[0], al[1], al[2], al[3], ah[0], ah[1], ah[2], ah[3]};
    }

    __builtin_amdgcn_s_setprio(1);
#pragma unroll
    for (int mi = 0; mi < 4; ++mi)
#pragma unroll
      for (int ni = 0; ni < 4; ++ni)
        acc[mi][ni] = __builtin_amdgcn_mfma_scale_f32_16x16x128_f8f6f4(
            ag[mi], bg[ni], acc[mi][ni],
            0, 0,                    // cbsz=fp8(e4m3), blgp=fp8(e4m3)
            0, 0x7F7F7F7F,           // scale A: opsel 0, E8M0 1.0
            0, 0x7F7F7F7F);          // scale B: opsel 0, E8M0 1.0
    __builtin_amdgcn_s_setprio(0);

    asm volatile("s_waitcnt lgkmcnt(0)" ::: "memory");  // LDS reads done
    __builtin_amdgcn_s_barrier();      // buffer cur may be overwritten next
    __builtin_amdgcn_sched_barrier(0);
  }

  // in-tile diagonal ownership: row(quad*4+r) == col(c16) <=> quad==c16>>2, r==c16&3
  const bool ownDiag = (quad == (c16 >> 2));
  const int rdiag = c16 & 3;

  // ---- positive pairs (pre-exp): sum 4*dot over this block's diagonal ----
  if (isPos && wm == wn) {
    float p = 0.f;
    if (ownDiag) {
#pragma unroll
      for (int mi = 0; mi < 4; ++mi) p += acc[mi][mi][rdiag];
    }
#pragma unroll
    for (int m = 1; m < 64; m <<= 1) p += __shfl_xor(p, m);
    if (lane == 0) atomicAdd(possum, 4.0f * p);
  }

  // ---- e = exp(2*sim) in place ----
#pragma unroll
  for (int mi = 0; mi < 4; ++mi)
#pragma unroll
    for (int ni = 0; ni < 4; ++ni)
#pragma unroll
      for (int r = 0; r < 4; ++r)
        acc[mi][ni][r] = __expf(2.0f * acc[mi][ni][r]);

  // ---- diagonal removal (diag blocks): zero exp(sim_ii) ----
  if (diag && wm == wn && ownDiag) {
#pragma unroll
    for (int mi = 0; mi < 4; ++mi) acc[mi][mi][rdiag] = 0.f;
  }

  if (t < TILE) { lrow[t] = 0.f; lcol[t] = 0.f; }
  __syncthreads();

  // row sums: reduce over ni (in-register) and c16 (shfl over lane bits 0-3)
#pragma unroll
  for (int mi = 0; mi < 4; ++mi) {
#pragma unroll
    for (int r = 0; r < 4; ++r) {
      float e = acc[mi][0][r] + acc[mi][1][r] + acc[mi][2][r] + acc[mi][3][r];
      e += __shfl_xor(e, 1);
      e += __shfl_xor(e, 2);
      e += __shfl_xor(e, 4);
      e += __shfl_xor(e, 8);
      if (c16 == 0) atomicAdd(&lrow[wm * 64 + mi * 16 + quad * 4 + r], e);
    }
  }
  // col sums: reduce over mi,r (in-register) and quad (shfl over lane bits 4-5)
  if (!diag) {
#pragma unroll
    for (int ni = 0; ni < 4; ++ni) {
      float g = 0.f;
#pragma unroll
      for (int mi = 0; mi < 4; ++mi)
#pragma unroll
        for (int r = 0; r < 4; ++r) g += acc[mi][ni][r];
      g += __shfl_xor(g, 16);
      g += __shfl_xor(g, 32);
      if (quad == 0) atomicAdd(&lcol[wn * 64 + ni * 16 + c16], g);
    }
  }
  __syncthreads();
  if (t < TILE) {
    atomicAdd(&rowsum[rowA + t], lrow[t]);
    if (!diag) atomicAdd(&rowsum[rowB + t], lcol[t]);
  }
}

// ---------------- finalize: loss = (sum_i log(rowsum_i) - possum) / NROWS ----
__global__ __launch_bounds__(256) void nt_finalize(const float* __restrict__ rowsum,
                                                   const float* __restrict__ possum,
                                                   float* __restrict__ out) {
  const int t = threadIdx.x;
  const int i = blockIdx.x * 256 + t;
  float v = logf(rowsum[i]);
#pragma unroll
  for (int m = 1; m < 64; m <<= 1) v += __shfl_xor(v, m);
  __shared__ float bsum[4];
  if ((t & 63) == 0) bsum[t >> 6] = v;
  __syncthreads();
  if (t == 0) {
    float s = bsum[0] + bsum[1] + bsum[2] + bsum[3];
    if (blockIdx.x == 0) s -= possum[0];
    atomicAdd(out, s * (1.0f / NROWS));
  }
}

extern "C" void kernel_launch(void* const* d_in, const int* in_sizes, int n_in,
                              void* d_out, int out_size, void* d_ws, size_t ws_size,
                              hipStream_t stream) {
  const float* zi = (const float*)d_in[0];
  const float* zj = (const float*)d_in[1];
  float* out = (float*)d_out;

  // ws layout: zq (8192*512 fp8 = 4 MB) | rowsum (8192 f32) | possum (1 f32)
  u8* zq = (u8*)d_ws;
  float* rowsum = (float*)((char*)d_ws + (size_t)NROWS * KD);
  float* possum = rowsum + NROWS;

  nt_normalize<<<NROWS / 4, 256, 0, stream>>>(zi, zj, zq, rowsum, possum, out);
  nt_gemm<<<NT * (NT + 1) / 2, 256, 0, stream>>>(zq, rowsum, possum);
  nt_finalize<<<NROWS / 256, 256, 0, stream>>>(rowsum, possum, out);
}